// Round 2
// baseline (659.167 us; speedup 1.0000x reference)
//
#include <hip/hip_runtime.h>
#include <stdint.h>

typedef unsigned short u16;
typedef __attribute__((ext_vector_type(8))) u16 u16x8;
typedef __attribute__((ext_vector_type(8))) __bf16 bf16x8;
typedef __attribute__((ext_vector_type(4))) float f32x4;

#define L2E 1.4426950408889634f

__device__ __forceinline__ float bf2f(u16 u) {
  union { unsigned i; float f; } v; v.i = ((unsigned)u) << 16; return v.f;
}
__device__ __forceinline__ u16 f2bf_rne(float f) {
  union { float f; unsigned u; } v; v.f = f;
  const unsigned r = v.u + 0x7FFFu + ((v.u >> 16) & 1u);
  return (u16)(r >> 16);
}
__device__ __forceinline__ bf16x8 ldb(const u16* p) {
  u16x8 v = *reinterpret_cast<const u16x8*>(p);
  return __builtin_bit_cast(bf16x8, v);
}
// fp32 -> split bf16 (hi + lo), 8 consecutive elements
__device__ __forceinline__ void ld_split8(const float* p, bf16x8& h, bf16x8& l) {
  const float4 v0 = *reinterpret_cast<const float4*>(p);
  const float4 v1 = *reinterpret_cast<const float4*>(p + 4);
  const float f[8] = {v0.x, v0.y, v0.z, v0.w, v1.x, v1.y, v1.z, v1.w};
  u16x8 hu, lu;
#pragma unroll
  for (int i = 0; i < 8; ++i) {
    const u16 hb = f2bf_rne(f[i]);
    hu[i] = hb;
    lu[i] = f2bf_rne(f[i] - bf2f(hb));
  }
  h = __builtin_bit_cast(bf16x8, hu);
  l = __builtin_bit_cast(bf16x8, lu);
}
__device__ __forceinline__ f32x4 mfma16(bf16x8 a, bf16x8 b, f32x4 c) {
  return __builtin_amdgcn_mfma_f32_16x16x32_bf16(a, b, c, 0, 0, 0);
}
__device__ __forceinline__ float sigm(float x) {
  return 1.0f / (1.0f + exp2f(-L2E * x));
}
__device__ __forceinline__ float tanh_(float x) {
  return 1.0f - 2.0f / (1.0f + exp2f(2.0f * L2E * x));
}

// ---------------------------------------------------------------------------
// K0: fold W2[a][k] = sum_f W_lfc[a,f] * W_loc[f,c,dk]  (k = c*31+dk, pad 64)
//     + zero the ctx accumulator (ws is re-poisoned 0xAA before every launch)
// ---------------------------------------------------------------------------
__global__ __launch_bounds__(128) void k0_prep(
    const float* __restrict__ Wloc, const float* __restrict__ Wlfc,
    u16* __restrict__ w2b, float* __restrict__ ctx)
{
  const int k = blockIdx.x, a = threadIdx.x;   // grid 64, block 128
  float v = 0.0f;
  if (k < 62) {
    const int c = (k >= 31) ? 1 : 0, dk = k - c * 31;
    for (int f = 0; f < 32; ++f)
      v += Wlfc[a * 32 + f] * Wloc[f * 62 + c * 31 + dk];
  }
  w2b[a * 64 + k] = f2bf_rne(v);
  ctx[k * 256 + a]       = 0.0f;
  ctx[k * 256 + 128 + a] = 0.0f;
}

// ---------------------------------------------------------------------------
// K1: attention LSTM. gates = [lf|actx|ah] @ [Wih|Whh]^T + b. Split-bf16 MFMA.
// ---------------------------------------------------------------------------
__global__ __launch_bounds__(256) void k1_attn_lstm(
    const float* __restrict__ lf, const float* __restrict__ actx,
    const float* __restrict__ ah_in, const float* __restrict__ ac_in,
    const float* __restrict__ Wih, const float* __restrict__ Whh,
    const float* __restrict__ bih, const float* __restrict__ bhh,
    float* __restrict__ ah_f, u16* __restrict__ xd)
{
  const int tid = threadIdx.x;
  const int w = tid >> 6, lane = tid & 63, quad = lane >> 4, l16 = lane & 15;
  const int jb = blockIdx.x * 16;
  const int mA = w * 16 + l16;
  f32x4 acc[4] = {{0,0,0,0},{0,0,0,0},{0,0,0,0},{0,0,0,0}};
  for (int kb = 0; kb < 1408; kb += 32) {
    const int k = kb + quad * 8;
    const float* ap;
    if (k < 128)      ap = lf    + mA * 128  + k;
    else if (k < 384) ap = actx  + mA * 256  + (k - 128);
    else              ap = ah_in + mA * 1024 + (k - 384);
    bf16x8 a_h, a_l; ld_split8(ap, a_h, a_l);
#pragma unroll
    for (int g = 0; g < 4; ++g) {
      const int n = g * 1024 + jb + l16;
      const float* bp = (k < 384) ? (Wih + n * 384 + k) : (Whh + n * 1024 + (k - 384));
      bf16x8 b_h, b_l; ld_split8(bp, b_h, b_l);
      acc[g] = mfma16(a_h, b_h, acc[g]);
      acc[g] = mfma16(a_h, b_l, acc[g]);
      acc[g] = mfma16(a_l, b_h, acc[g]);
    }
  }
  const int j = jb + l16;
  const float bi_ = bih[j]        + bhh[j];
  const float bff = bih[1024 + j] + bhh[1024 + j];
  const float bg_ = bih[2048 + j] + bhh[2048 + j];
  const float bo_ = bih[3072 + j] + bhh[3072 + j];
#pragma unroll
  for (int r = 0; r < 4; ++r) {
    const int m = w * 16 + quad * 4 + r;
    const float pi = acc[0][r] + bi_;
    const float pf = acc[1][r] + bff;
    const float pg = acc[2][r] + bg_;
    const float po = acc[3][r] + bo_;
    const float c2 = sigm(pf) * ac_in[m * 1024 + j] + sigm(pi) * tanh_(pg);
    const float h2 = sigm(po) * tanh_(c2);
    ah_f[m * 1024 + j] = h2;
    xd[m * 1280 + j]   = f2bf_rne(h2);
  }
}

// ---------------------------------------------------------------------------
// K2a: pq[b][a] = ah[b] . W_q[a]   (wave per (a, 4 batch rows)), pure fp32
// ---------------------------------------------------------------------------
__global__ __launch_bounds__(256) void k2a_pq(
    const float* __restrict__ ah_f, const float* __restrict__ Wq, float* __restrict__ pq)
{
  const int lane = threadIdx.x & 63;
  const int wid = blockIdx.x * 4 + (threadIdx.x >> 6);   // 0..2047
  const int a = wid & 127, bg = wid >> 7;                // a, batch group
  float s[4] = {0, 0, 0, 0};
  for (int k = lane; k < 1024; k += 64) {
    const float wq = Wq[a * 1024 + k];
#pragma unroll
    for (int i = 0; i < 4; ++i) s[i] += wq * ah_f[(bg * 4 + i) * 1024 + k];
  }
#pragma unroll
  for (int i = 0; i < 4; ++i) {
    float v = s[i];
    for (int off = 1; off < 64; off <<= 1) v += __shfl_xor(v, off, 64);
    if (lane == 0) pq[(bg * 4 + i) * 128 + a] = v;
  }
}

// ---------------------------------------------------------------------------
// K2: per (b, 32-t tile): folded location conv as bf16 MFMA, then
// e[b,t] = sum_a Wv[a]*tanh(pq + pm + loc), masked -> fp32.
// ---------------------------------------------------------------------------
__global__ __launch_bounds__(256) void k2_energy(
    const float* __restrict__ aw, const float* __restrict__ awc,
    const float* __restrict__ pm, const float* __restrict__ Wv,
    const float* __restrict__ pq, const u16* __restrict__ w2b,
    const int* __restrict__ msk, float* __restrict__ e_g)
{
  __shared__ __align__(16) u16 awin[2][64];
  __shared__ __align__(16) u16 pms[32 * 128];
  __shared__ __align__(16) u16 w2s[128 * 64];
  __shared__ float wvs[128];
  __shared__ float pqs[128];
  __shared__ float es[32];
  const int b = blockIdx.y, t0 = blockIdx.x * 32, tid = threadIdx.x;

  if (tid < 128) {
    const int c = tid >> 6, ii = tid & 63;
    const int t = t0 - 15 + ii;
    float v = 0.0f;
    if (ii < 62 && t >= 0 && t < 2048) v = (c ? awc : aw)[b * 2048 + t];
    awin[c][ii] = f2bf_rne(v);
    wvs[tid] = Wv[tid];
    pqs[tid] = pq[b * 128 + tid];
  }
  if (tid < 32) es[tid] = 0.0f;
  {
    // stage 32x128 fp32 pm tile -> bf16 LDS (16 elements / thread)
    const float* src = pm + (size_t)b * 262144 + (size_t)t0 * 128;
    const int i = tid * 16;
#pragma unroll
    for (int q = 0; q < 4; ++q) {
      const float4 v = *reinterpret_cast<const float4*>(&src[i + q * 4]);
      pms[i + q * 4 + 0] = f2bf_rne(v.x);
      pms[i + q * 4 + 1] = f2bf_rne(v.y);
      pms[i + q * 4 + 2] = f2bf_rne(v.z);
      pms[i + q * 4 + 3] = f2bf_rne(v.w);
    }
  }
  {
    const int i = tid * 32;
#pragma unroll
    for (int q = 0; q < 4; ++q)
      *reinterpret_cast<u16x8*>(&w2s[i + q * 8]) = *reinterpret_cast<const u16x8*>(&w2b[i + q * 8]);
  }
  __syncthreads();

  const int w = tid >> 6, lane = tid & 63, quad = lane >> 4, l16 = lane & 15;
  const int mt = w & 1, ng = w >> 1;   // m-tile (t-half), n-group (a-half)
  f32x4 acc[4] = {{0,0,0,0},{0,0,0,0},{0,0,0,0},{0,0,0,0}};
#pragma unroll
  for (int ks = 0; ks < 2; ++ks) {
    bf16x8 af;
    const int m = mt * 16 + l16;
#pragma unroll
    for (int jj = 0; jj < 8; ++jj) {
      const int k = ks * 32 + quad * 8 + jj;
      u16 v = 0;
      if (k < 62) { const int c = (k >= 31) ? 1 : 0; const int dk = k - c * 31; v = awin[c][m + dk]; }
      af[jj] = __builtin_bit_cast(__bf16, v);
    }
#pragma unroll
    for (int p = 0; p < 4; ++p) {
      const int a = (ng * 4 + p) * 16 + l16;
      bf16x8 bfr = *reinterpret_cast<const bf16x8*>(&w2s[a * 64 + ks * 32 + quad * 8]);
      acc[p] = mfma16(af, bfr, acc[p]);
    }
  }
#pragma unroll
  for (int r = 0; r < 4; ++r) {
    const int tl = mt * 16 + quad * 4 + r;
    float part = 0.0f;
#pragma unroll
    for (int p = 0; p < 4; ++p) {
      const int a = (ng * 4 + p) * 16 + l16;
      const float x = pqs[a] + bf2f(pms[tl * 128 + a]) + acc[p][r];
      part += wvs[a] * tanh_(x);
    }
    part += __shfl_xor(part, 1, 64);
    part += __shfl_xor(part, 2, 64);
    part += __shfl_xor(part, 4, 64);
    part += __shfl_xor(part, 8, 64);
    if (l16 == 0) atomicAdd(&es[tl], part);
  }
  __syncthreads();
  if (tid < 32) {
    const int t = t0 + tid;
    e_g[b * 2048 + t] = msk[b * 2048 + t] ? -1e30f : es[tid];
  }
}

// ---------------------------------------------------------------------------
// K3a: softmax over T per batch row; fp32 weights to ws + fp32 output.
// ---------------------------------------------------------------------------
__global__ __launch_bounds__(256) void k3a_softmax(
    const float* __restrict__ e_g, float* __restrict__ w_f, float* __restrict__ out_w)
{
  const int b = blockIdx.x, tid = threadIdx.x;
  __shared__ float red[4];
  float v[8];
  float mx = -3.0e38f;
#pragma unroll
  for (int i = 0; i < 8; ++i) { v[i] = e_g[b * 2048 + tid + i * 256]; mx = fmaxf(mx, v[i]); }
  for (int off = 1; off < 64; off <<= 1) mx = fmaxf(mx, __shfl_xor(mx, off, 64));
  if ((tid & 63) == 0) red[tid >> 6] = mx;
  __syncthreads();
  mx = fmaxf(fmaxf(red[0], red[1]), fmaxf(red[2], red[3]));
  float ex[8], s = 0.0f;
#pragma unroll
  for (int i = 0; i < 8; ++i) { ex[i] = exp2f((v[i] - mx) * L2E); s += ex[i]; }
  for (int off = 1; off < 64; off <<= 1) s += __shfl_xor(s, off, 64);
  __syncthreads();
  if ((tid & 63) == 0) red[tid >> 6] = s;
  __syncthreads();
  const float rs = 1.0f / (red[0] + red[1] + red[2] + red[3]);
#pragma unroll
  for (int i = 0; i < 8; ++i) {
    const int t = tid + i * 256;
    const float wv = ex[i] * rs;
    w_f[b * 2048 + t]   = wv;
    out_w[b * 2048 + t] = wv;
  }
}

// ---------------------------------------------------------------------------
// K3b: ctx[b][e] += sum over 256-t chunk of w[b,t]*mem[b,t,e] (fp32, coalesced)
// ---------------------------------------------------------------------------
__global__ __launch_bounds__(256) void k3b_ctx(
    const float* __restrict__ w_f, const float* __restrict__ mem, float* __restrict__ ctx)
{
  const int b = blockIdx.y, tc = blockIdx.x, tid = threadIdx.x;
  __shared__ float wsm[256];
  wsm[tid] = w_f[b * 2048 + tc * 256 + tid];
  __syncthreads();
  const float* mp = mem + (size_t)b * 524288 + (size_t)tc * 65536 + tid;
  float acc = 0.0f;
#pragma unroll 8
  for (int t = 0; t < 256; ++t) acc += wsm[t] * mp[(size_t)t * 256];
  atomicAdd(&ctx[b * 256 + tid], acc);
}

// ---------------------------------------------------------------------------
// K3c: ctx fp32 -> bf16 into xd[:,1024:1280] and dhac[:,1024:1280]
// ---------------------------------------------------------------------------
__global__ __launch_bounds__(256) void k3c_cvt(
    const float* __restrict__ ctx, u16* __restrict__ xd, u16* __restrict__ dhac)
{
  const int b = blockIdx.x, e = threadIdx.x;
  const u16 v = f2bf_rne(ctx[b * 256 + e]);
  xd[b * 1280 + 1024 + e]   = v;
  dhac[b * 1280 + 1024 + e] = v;
}

// ---------------------------------------------------------------------------
// K4: decoder LSTM (K = 1280 + 1024 = 2304). A: xd bf16 / dh fp32-split.
// ---------------------------------------------------------------------------
__global__ __launch_bounds__(256) void k4_dec_lstm(
    const u16* __restrict__ xd, const float* __restrict__ dh_in, const float* __restrict__ dc_in,
    const float* __restrict__ Wih, const float* __restrict__ Whh,
    const float* __restrict__ bih, const float* __restrict__ bhh,
    u16* __restrict__ dhac)
{
  const int tid = threadIdx.x;
  const int w = tid >> 6, lane = tid & 63, quad = lane >> 4, l16 = lane & 15;
  const int jb = blockIdx.x * 16;
  const int mA = w * 16 + l16;
  const u16x8 zu = {0, 0, 0, 0, 0, 0, 0, 0};
  const bf16x8 zb = __builtin_bit_cast(bf16x8, zu);
  f32x4 acc[4] = {{0,0,0,0},{0,0,0,0},{0,0,0,0},{0,0,0,0}};
  for (int kb = 0; kb < 2304; kb += 32) {
    const int k = kb + quad * 8;
    bf16x8 a_h, a_l;
    if (k < 1280) { a_h = ldb(xd + mA * 1280 + k); a_l = zb; }
    else          { ld_split8(dh_in + mA * 1024 + (k - 1280), a_h, a_l); }
#pragma unroll
    for (int g = 0; g < 4; ++g) {
      const int n = g * 1024 + jb + l16;
      const float* bp = (k < 1280) ? (Wih + n * 1280 + k) : (Whh + n * 1024 + (k - 1280));
      bf16x8 b_h, b_l; ld_split8(bp, b_h, b_l);
      acc[g] = mfma16(a_h, b_h, acc[g]);
      acc[g] = mfma16(a_h, b_l, acc[g]);
      acc[g] = mfma16(a_l, b_h, acc[g]);
    }
  }
  const int j = jb + l16;
  const float bi_ = bih[j]        + bhh[j];
  const float bff = bih[1024 + j] + bhh[1024 + j];
  const float bg_ = bih[2048 + j] + bhh[2048 + j];
  const float bo_ = bih[3072 + j] + bhh[3072 + j];
#pragma unroll
  for (int r = 0; r < 4; ++r) {
    const int m = w * 16 + quad * 4 + r;
    const float pi = acc[0][r] + bi_;
    const float pf = acc[1][r] + bff;
    const float pg = acc[2][r] + bg_;
    const float po = acc[3][r] + bo_;
    const float c2 = sigm(pf) * dc_in[m * 1024 + j] + sigm(pi) * tanh_(pg);
    const float h2 = sigm(po) * tanh_(c2);
    dhac[m * 1280 + j] = f2bf_rne(h2);
  }
}

// ---------------------------------------------------------------------------
// K5: heads. Blocks 0..3: decoder_output (MFMA, B=Wp split).
//     Blocks 4..19: stop gate (fp32 dot, wave per batch row).
// ---------------------------------------------------------------------------
__global__ __launch_bounds__(256) void k5_heads(
    const u16* __restrict__ dhac, const float* __restrict__ Wp, const float* __restrict__ bp,
    const float* __restrict__ Wg, const float* __restrict__ bg, float* __restrict__ out)
{
  const int tid = threadIdx.x, w = tid >> 6, lane = tid & 63, quad = lane >> 4, l16 = lane & 15;
  if (blockIdx.x < 4) {
    const int n = blockIdx.x * 64 + w * 16 + l16;
    f32x4 acc[4] = {{0,0,0,0},{0,0,0,0},{0,0,0,0},{0,0,0,0}};
    for (int kb = 0; kb < 1280; kb += 32) {
      const int k = kb + quad * 8;
      bf16x8 b_h, b_l; ld_split8(Wp + n * 1280 + k, b_h, b_l);
#pragma unroll
      for (int mt = 0; mt < 4; ++mt) {
        bf16x8 af = ldb(dhac + (mt * 16 + l16) * 1280 + k);
        acc[mt] = mfma16(af, b_h, acc[mt]);
        acc[mt] = mfma16(af, b_l, acc[mt]);
      }
    }
    const float bb = bp[n];
#pragma unroll
    for (int mt = 0; mt < 4; ++mt)
#pragma unroll
      for (int r = 0; r < 4; ++r)
        out[(mt * 16 + quad * 4 + r) * 256 + n] = acc[mt][r] + bb;
  } else {
    const int bb = (blockIdx.x - 4) * 4 + w;   // batch row 0..63
    float s = 0.0f;
    for (int k = lane; k < 1280; k += 64) s += bf2f(dhac[bb * 1280 + k]) * Wg[k];
    for (int off = 1; off < 64; off <<= 1) s += __shfl_xor(s, off, 64);
    if (lane == 0) out[16384 + bb] = s + bg[0];
  }
}

extern "C" void kernel_launch(void* const* d_in, const int* in_sizes, int n_in,
                              void* d_out, int out_size, void* d_ws, size_t ws_size,
                              hipStream_t stream)
{
  const float* lf    = (const float*)d_in[0];
  const float* ah0   = (const float*)d_in[1];
  const float* ac0   = (const float*)d_in[2];
  const float* aw    = (const float*)d_in[3];
  const float* awc   = (const float*)d_in[4];
  const float* actx  = (const float*)d_in[5];
  const float* dh0   = (const float*)d_in[6];
  const float* dc0   = (const float*)d_in[7];
  const float* mem   = (const float*)d_in[8];
  const float* pm    = (const float*)d_in[9];
  const float* Wih_a = (const float*)d_in[10];
  const float* Whh_a = (const float*)d_in[11];
  const float* bih_a = (const float*)d_in[12];
  const float* bhh_a = (const float*)d_in[13];
  const float* Wq    = (const float*)d_in[14];
  const float* Wv    = (const float*)d_in[15];
  const float* Wloc  = (const float*)d_in[16];
  const float* Wlfc  = (const float*)d_in[17];
  const float* Wih_d = (const float*)d_in[18];
  const float* Whh_d = (const float*)d_in[19];
  const float* bih_d = (const float*)d_in[20];
  const float* bhh_d = (const float*)d_in[21];
  const float* Wp    = (const float*)d_in[22];
  const float* bp    = (const float*)d_in[23];
  const float* Wg    = (const float*)d_in[24];
  const float* bg    = (const float*)d_in[25];
  const int* msk     = (const int*)d_in[26];

  // workspace layout: fp32 region then bf16 region (~1.8 MB)
  float* wsf  = (float*)d_ws;
  float* ah_f = wsf;              // 64*1024
  float* pq   = wsf + 65536;      // 64*128
  float* e_g  = wsf + 73728;      // 64*2048
  float* w_f  = wsf + 204800;     // 64*2048
  float* ctx  = wsf + 335872;     // 64*256
  u16* xd     = (u16*)(wsf + 352256);  // 64*1280 bf16 (ah | ctx)
  u16* dhac   = xd + 81920;            // 64*1280 bf16 (dh | ctx)
  u16* w2b    = dhac + 81920;          // 128*64 bf16 folded loc weights

  float* out   = (float*)d_out;
  float* out_w = out + 16448;     // after proj(16384) + stop(64)

  k0_prep     <<<64, 128, 0, stream>>>(Wloc, Wlfc, w2b, ctx);
  k1_attn_lstm<<<64, 256, 0, stream>>>(lf, actx, ah0, ac0, Wih_a, Whh_a, bih_a, bhh_a, ah_f, xd);
  k2a_pq      <<<512, 256, 0, stream>>>(ah_f, Wq, pq);
  k2_energy   <<<dim3(64, 64), 256, 0, stream>>>(aw, awc, pm, Wv, pq, w2b, msk, e_g);
  k3a_softmax <<<64, 256, 0, stream>>>(e_g, w_f, out_w);
  k3b_ctx     <<<dim3(8, 64), 256, 0, stream>>>(w_f, mem, ctx);
  k3c_cvt     <<<64, 256, 0, stream>>>(ctx, xd, dhac);
  k4_dec_lstm <<<64, 256, 0, stream>>>(xd, dh0, dc0, Wih_d, Whh_d, bih_d, bhh_d, dhac);
  k5_heads    <<<20, 256, 0, stream>>>(dhac, Wp, bp, Wg, bg, out);
}

// Round 3
// 401.305 us; speedup vs baseline: 1.6426x; 1.6426x over previous
//
#include <hip/hip_runtime.h>
#include <stdint.h>

typedef unsigned short u16;
typedef __attribute__((ext_vector_type(8))) u16 u16x8;
typedef __attribute__((ext_vector_type(8))) __bf16 bf16x8;
typedef __attribute__((ext_vector_type(4))) float f32x4;

#define L2E 1.4426950408889634f

__device__ __forceinline__ float bf2f(u16 u) {
  union { unsigned i; float f; } v; v.i = ((unsigned)u) << 16; return v.f;
}
__device__ __forceinline__ u16 f2bf_rne(float f) {
  union { float f; unsigned u; } v; v.f = f;
  const unsigned r = v.u + 0x7FFFu + ((v.u >> 16) & 1u);
  return (u16)(r >> 16);
}
__device__ __forceinline__ bf16x8 ldb(const u16* p) {
  u16x8 v = *reinterpret_cast<const u16x8*>(p);
  return __builtin_bit_cast(bf16x8, v);
}
// fp32 -> split bf16 via truncation: f = hi + lo + O(2^-16 |f|), ~4 VALU/elem
__device__ __forceinline__ void split8t(const float* p, bf16x8& h, bf16x8& l) {
  const float4 v0 = *reinterpret_cast<const float4*>(p);
  const float4 v1 = *reinterpret_cast<const float4*>(p + 4);
  const float f[8] = {v0.x, v0.y, v0.z, v0.w, v1.x, v1.y, v1.z, v1.w};
  u16x8 hu, lu;
#pragma unroll
  for (int i = 0; i < 8; ++i) {
    union { float f; unsigned u; } a; a.f = f[i];
    hu[i] = (u16)(a.u >> 16);
    union { float f; unsigned u; } hf; hf.u = a.u & 0xFFFF0000u;
    union { float f; unsigned u; } lo; lo.f = f[i] - hf.f;
    lu[i] = (u16)(lo.u >> 16);
  }
  h = __builtin_bit_cast(bf16x8, hu);
  l = __builtin_bit_cast(bf16x8, lu);
}
__device__ __forceinline__ f32x4 mfma16(bf16x8 a, bf16x8 b, f32x4 c) {
  return __builtin_amdgcn_mfma_f32_16x16x32_bf16(a, b, c, 0, 0, 0);
}
__device__ __forceinline__ float sigm(float x) {
  return 1.0f / (1.0f + exp2f(-L2E * x));
}
__device__ __forceinline__ float tanh_(float x) {
  return 1.0f - 2.0f / (1.0f + exp2f(2.0f * L2E * x));
}

// ---------------------------------------------------------------------------
// K0: fold W2[a][k] = sum_f W_lfc[a,f] * W_loc[f,c,dk]  (k = c*31+dk, pad 64)
// ---------------------------------------------------------------------------
__global__ __launch_bounds__(128) void k0_prep(
    const float* __restrict__ Wloc, const float* __restrict__ Wlfc,
    u16* __restrict__ w2b)
{
  const int k = blockIdx.x, a = threadIdx.x;   // grid 64, block 128
  float v = 0.0f;
  if (k < 62) {
    const int c = (k >= 31) ? 1 : 0, dk = k - c * 31;
    for (int f = 0; f < 32; ++f)
      v += Wlfc[a * 32 + f] * Wloc[f * 62 + c * 31 + dk];
  }
  w2b[a * 64 + k] = f2bf_rne(v);
}

// ---------------------------------------------------------------------------
// K1 GEMM: split-K partial of gates_a = [lf|actx|ah] @ [Wih|Whh]^T.
// grid (64 j-tiles, KSA chunks); wave = gate g; each weight byte read once.
// ---------------------------------------------------------------------------
#define KSA 8
__global__ __launch_bounds__(256) void k1_gemm(
    const float* __restrict__ lf, const float* __restrict__ actx,
    const float* __restrict__ ah_in,
    const float* __restrict__ Wih, const float* __restrict__ Whh,
    float* __restrict__ gates)
{
  const int tid = threadIdx.x;
  const int g = tid >> 6, lane = tid & 63, quad = lane >> 4, l16 = lane & 15;
  const int jb = blockIdx.x * 16, ks = blockIdx.y;
  const int n = g * 1024 + jb + l16;
  const int s0 = (ks * 44) / KSA, s1 = ((ks + 1) * 44) / KSA;
  f32x4 acc[4] = {{0,0,0,0},{0,0,0,0},{0,0,0,0},{0,0,0,0}};
  for (int s = s0; s < s1; ++s) {
    const int kb = s * 32, k = kb + quad * 8;
    const float* bp = (k < 384) ? (Wih + n * 384 + k) : (Whh + n * 1024 + (k - 384));
    bf16x8 b_h, b_l; split8t(bp, b_h, b_l);
#pragma unroll
    for (int mt = 0; mt < 4; ++mt) {
      const int mA = mt * 16 + l16;
      const float* ap;
      if (k < 128)      ap = lf    + mA * 128  + k;
      else if (k < 384) ap = actx  + mA * 256  + (k - 128);
      else              ap = ah_in + mA * 1024 + (k - 384);
      bf16x8 a_h, a_l; split8t(ap, a_h, a_l);
      acc[mt] = mfma16(a_h, b_h, acc[mt]);
      acc[mt] = mfma16(a_h, b_l, acc[mt]);
      acc[mt] = mfma16(a_l, b_h, acc[mt]);
    }
  }
#pragma unroll
  for (int mt = 0; mt < 4; ++mt)
#pragma unroll
    for (int r = 0; r < 4; ++r)
      atomicAdd(&gates[(mt * 16 + quad * 4 + r) * 4096 + n], acc[mt][r]);
}

// ---------------------------------------------------------------------------
// K1 epilogue: LSTM nonlinearity -> ah_f fp32 + xd bf16 (cols 0..1023)
// ---------------------------------------------------------------------------
__global__ __launch_bounds__(256) void k1_epi(
    const float* __restrict__ gates, const float* __restrict__ ac_in,
    const float* __restrict__ bih, const float* __restrict__ bhh,
    float* __restrict__ ah_f, u16* __restrict__ xd)
{
  const int lin = blockIdx.x * 256 + threadIdx.x;   // 64*1024
  const int m = lin >> 10, j = lin & 1023;
  const float pi = gates[m * 4096 + j]        + bih[j]        + bhh[j];
  const float pf = gates[m * 4096 + 1024 + j] + bih[1024 + j] + bhh[1024 + j];
  const float pg = gates[m * 4096 + 2048 + j] + bih[2048 + j] + bhh[2048 + j];
  const float po = gates[m * 4096 + 3072 + j] + bih[3072 + j] + bhh[3072 + j];
  const float c2 = sigm(pf) * ac_in[m * 1024 + j] + sigm(pi) * tanh_(pg);
  const float h2 = sigm(po) * tanh_(c2);
  ah_f[m * 1024 + j] = h2;
  xd[m * 1280 + j]   = f2bf_rne(h2);
}

// ---------------------------------------------------------------------------
// K2a: pq[b][a] = ah[b] . W_q[a]   (wave per (a, 4 batch rows)), pure fp32
// ---------------------------------------------------------------------------
__global__ __launch_bounds__(256) void k2a_pq(
    const float* __restrict__ ah_f, const float* __restrict__ Wq, float* __restrict__ pq)
{
  const int lane = threadIdx.x & 63;
  const int wid = blockIdx.x * 4 + (threadIdx.x >> 6);   // 0..2047
  const int a = wid & 127, bg = wid >> 7;
  float s[4] = {0, 0, 0, 0};
  for (int k = lane; k < 1024; k += 64) {
    const float wq = Wq[a * 1024 + k];
#pragma unroll
    for (int i = 0; i < 4; ++i) s[i] += wq * ah_f[(bg * 4 + i) * 1024 + k];
  }
#pragma unroll
  for (int i = 0; i < 4; ++i) {
    float v = s[i];
    for (int off = 1; off < 64; off <<= 1) v += __shfl_xor(v, off, 64);
    if (lane == 0) pq[(bg * 4 + i) * 128 + a] = v;
  }
}

// ---------------------------------------------------------------------------
// K2: per (b, 32-t tile): folded location conv as bf16 MFMA, then
// e[b,t] = sum_a Wv[a]*tanh(pq + pm + loc), masked -> fp32.
// ---------------------------------------------------------------------------
__global__ __launch_bounds__(256) void k2_energy(
    const float* __restrict__ aw, const float* __restrict__ awc,
    const float* __restrict__ pm, const float* __restrict__ Wv,
    const float* __restrict__ pq, const u16* __restrict__ w2b,
    const int* __restrict__ msk, float* __restrict__ e_g)
{
  __shared__ __align__(16) u16 awin[2][64];
  __shared__ __align__(16) u16 pms[32 * 128];
  __shared__ __align__(16) u16 w2s[128 * 64];
  __shared__ float wvs[128];
  __shared__ float pqs[128];
  __shared__ float es[32];
  const int b = blockIdx.y, t0 = blockIdx.x * 32, tid = threadIdx.x;

  if (tid < 128) {
    const int c = tid >> 6, ii = tid & 63;
    const int t = t0 - 15 + ii;
    float v = 0.0f;
    if (ii < 62 && t >= 0 && t < 2048) v = (c ? awc : aw)[b * 2048 + t];
    awin[c][ii] = f2bf_rne(v);
    wvs[tid] = Wv[tid];
    pqs[tid] = pq[b * 128 + tid];
  }
  if (tid < 32) es[tid] = 0.0f;
  {
    const float* src = pm + (size_t)b * 262144 + (size_t)t0 * 128;
    const int i = tid * 16;
#pragma unroll
    for (int q = 0; q < 4; ++q) {
      const float4 v = *reinterpret_cast<const float4*>(&src[i + q * 4]);
      pms[i + q * 4 + 0] = f2bf_rne(v.x);
      pms[i + q * 4 + 1] = f2bf_rne(v.y);
      pms[i + q * 4 + 2] = f2bf_rne(v.z);
      pms[i + q * 4 + 3] = f2bf_rne(v.w);
    }
  }
  {
    const int i = tid * 32;
#pragma unroll
    for (int q = 0; q < 4; ++q)
      *reinterpret_cast<u16x8*>(&w2s[i + q * 8]) = *reinterpret_cast<const u16x8*>(&w2b[i + q * 8]);
  }
  __syncthreads();

  const int w = tid >> 6, lane = tid & 63, quad = lane >> 4, l16 = lane & 15;
  const int mt = w & 1, ng = w >> 1;
  f32x4 acc[4] = {{0,0,0,0},{0,0,0,0},{0,0,0,0},{0,0,0,0}};
#pragma unroll
  for (int ksx = 0; ksx < 2; ++ksx) {
    bf16x8 af;
    const int m = mt * 16 + l16;
#pragma unroll
    for (int jj = 0; jj < 8; ++jj) {
      const int k = ksx * 32 + quad * 8 + jj;
      u16 v = 0;
      if (k < 62) { const int c = (k >= 31) ? 1 : 0; const int dk = k - c * 31; v = awin[c][m + dk]; }
      af[jj] = __builtin_bit_cast(__bf16, v);
    }
#pragma unroll
    for (int p = 0; p < 4; ++p) {
      const int a = (ng * 4 + p) * 16 + l16;
      bf16x8 bfr = *reinterpret_cast<const bf16x8*>(&w2s[a * 64 + ksx * 32 + quad * 8]);
      acc[p] = mfma16(af, bfr, acc[p]);
    }
  }
#pragma unroll
  for (int r = 0; r < 4; ++r) {
    const int tl = mt * 16 + quad * 4 + r;
    float part = 0.0f;
#pragma unroll
    for (int p = 0; p < 4; ++p) {
      const int a = (ng * 4 + p) * 16 + l16;
      const float x = pqs[a] + bf2f(pms[tl * 128 + a]) + acc[p][r];
      part += wvs[a] * tanh_(x);
    }
    part += __shfl_xor(part, 1, 64);
    part += __shfl_xor(part, 2, 64);
    part += __shfl_xor(part, 4, 64);
    part += __shfl_xor(part, 8, 64);
    if (l16 == 0) atomicAdd(&es[tl], part);
  }
  __syncthreads();
  if (tid < 32) {
    const int t = t0 + tid;
    e_g[b * 2048 + t] = msk[b * 2048 + t] ? -1e30f : es[tid];
  }
}

// ---------------------------------------------------------------------------
// K3a: softmax over T per batch row; fp32 weights to ws + fp32 output.
// ---------------------------------------------------------------------------
__global__ __launch_bounds__(256) void k3a_softmax(
    const float* __restrict__ e_g, float* __restrict__ w_f, float* __restrict__ out_w)
{
  const int b = blockIdx.x, tid = threadIdx.x;
  __shared__ float red[4];
  float v[8];
  float mx = -3.0e38f;
#pragma unroll
  for (int i = 0; i < 8; ++i) { v[i] = e_g[b * 2048 + tid + i * 256]; mx = fmaxf(mx, v[i]); }
  for (int off = 1; off < 64; off <<= 1) mx = fmaxf(mx, __shfl_xor(mx, off, 64));
  if ((tid & 63) == 0) red[tid >> 6] = mx;
  __syncthreads();
  mx = fmaxf(fmaxf(red[0], red[1]), fmaxf(red[2], red[3]));
  float ex[8], s = 0.0f;
#pragma unroll
  for (int i = 0; i < 8; ++i) { ex[i] = exp2f((v[i] - mx) * L2E); s += ex[i]; }
  for (int off = 1; off < 64; off <<= 1) s += __shfl_xor(s, off, 64);
  __syncthreads();
  if ((tid & 63) == 0) red[tid >> 6] = s;
  __syncthreads();
  const float rs = 1.0f / (red[0] + red[1] + red[2] + red[3]);
#pragma unroll
  for (int i = 0; i < 8; ++i) {
    const int t = tid + i * 256;
    const float wv = ex[i] * rs;
    w_f[b * 2048 + t]   = wv;
    out_w[b * 2048 + t] = wv;
  }
}

// ---------------------------------------------------------------------------
// K3b: ctx[b][e] += sum_t w[b,t]*mem[b,t,e]. Lane owns float4 along E;
// waves split T; LDS cross-wave reduce; 1 atomic/element/block.
// ---------------------------------------------------------------------------
__global__ __launch_bounds__(256) void k3b_ctx(
    const float* __restrict__ w_f, const float* __restrict__ mem, float* __restrict__ ctx)
{
  const int b = blockIdx.y, tc = blockIdx.x, tid = threadIdx.x;
  const int w = tid >> 6, lane = tid & 63;
  __shared__ float wsm[256];
  __shared__ float red[4][256];
  wsm[tid] = w_f[b * 2048 + tc * 256 + tid];
  __syncthreads();
  const float* mp = mem + (size_t)b * 524288 + ((size_t)tc * 256 + w * 64) * 256 + lane * 4;
  f32x4 acc = {0, 0, 0, 0};
#pragma unroll 4
  for (int t = 0; t < 64; ++t) {
    const float wt = wsm[w * 64 + t];
    const float4 v = *reinterpret_cast<const float4*>(mp + (size_t)t * 256);
    acc[0] += wt * v.x; acc[1] += wt * v.y; acc[2] += wt * v.z; acc[3] += wt * v.w;
  }
#pragma unroll
  for (int i = 0; i < 4; ++i) red[w][lane * 4 + i] = acc[i];
  __syncthreads();
  const float s = red[0][tid] + red[1][tid] + red[2][tid] + red[3][tid];
  atomicAdd(&ctx[b * 256 + tid], s);
}

// ---------------------------------------------------------------------------
// K3c: ctx fp32 -> bf16 into xd[:,1024:1280] and dhac[:,1024:1280]
// ---------------------------------------------------------------------------
__global__ __launch_bounds__(256) void k3c_cvt(
    const float* __restrict__ ctx, u16* __restrict__ xd, u16* __restrict__ dhac)
{
  const int b = blockIdx.x, e = threadIdx.x;
  const u16 v = f2bf_rne(ctx[b * 256 + e]);
  xd[b * 1280 + 1024 + e]   = v;
  dhac[b * 1280 + 1024 + e] = v;
}

// ---------------------------------------------------------------------------
// K4 GEMM: split-K partial of gates_d = [xd(bf16) | dh(fp32)] @ [Wih|Whh]^T
// grid (64 j-tiles, 9 chunks of 256 k)
// ---------------------------------------------------------------------------
__global__ __launch_bounds__(256) void k4_gemm(
    const u16* __restrict__ xd, const float* __restrict__ dh_in,
    const float* __restrict__ Wih, const float* __restrict__ Whh,
    float* __restrict__ gates)
{
  const int tid = threadIdx.x;
  const int g = tid >> 6, lane = tid & 63, quad = lane >> 4, l16 = lane & 15;
  const int jb = blockIdx.x * 16, ks = blockIdx.y;
  const int n = g * 1024 + jb + l16;
  const int kb0 = ks * 256, kb1 = kb0 + 256;
  f32x4 acc[4] = {{0,0,0,0},{0,0,0,0},{0,0,0,0},{0,0,0,0}};
  for (int kb = kb0; kb < kb1; kb += 32) {
    const int k = kb + quad * 8;
    const float* bp = (k < 1280) ? (Wih + n * 1280 + k) : (Whh + n * 1024 + (k - 1280));
    bf16x8 b_h, b_l; split8t(bp, b_h, b_l);
    if (k < 1280) {
#pragma unroll
      for (int mt = 0; mt < 4; ++mt) {
        bf16x8 a_h = ldb(xd + (mt * 16 + l16) * 1280 + k);
        acc[mt] = mfma16(a_h, b_h, acc[mt]);
        acc[mt] = mfma16(a_h, b_l, acc[mt]);
      }
    } else {
#pragma unroll
      for (int mt = 0; mt < 4; ++mt) {
        bf16x8 a_h, a_l; split8t(dh_in + (mt * 16 + l16) * 1024 + (k - 1280), a_h, a_l);
        acc[mt] = mfma16(a_h, b_h, acc[mt]);
        acc[mt] = mfma16(a_h, b_l, acc[mt]);
        acc[mt] = mfma16(a_l, b_h, acc[mt]);
      }
    }
  }
#pragma unroll
  for (int mt = 0; mt < 4; ++mt)
#pragma unroll
    for (int r = 0; r < 4; ++r)
      atomicAdd(&gates[(mt * 16 + quad * 4 + r) * 4096 + n], acc[mt][r]);
}

// ---------------------------------------------------------------------------
// K4 epilogue: LSTM nonlinearity -> dhac bf16 (cols 0..1023)
// ---------------------------------------------------------------------------
__global__ __launch_bounds__(256) void k4_epi(
    const float* __restrict__ gates, const float* __restrict__ dc_in,
    const float* __restrict__ bih, const float* __restrict__ bhh,
    u16* __restrict__ dhac)
{
  const int lin = blockIdx.x * 256 + threadIdx.x;
  const int m = lin >> 10, j = lin & 1023;
  const float pi = gates[m * 4096 + j]        + bih[j]        + bhh[j];
  const float pf = gates[m * 4096 + 1024 + j] + bih[1024 + j] + bhh[1024 + j];
  const float pg = gates[m * 4096 + 2048 + j] + bih[2048 + j] + bhh[2048 + j];
  const float po = gates[m * 4096 + 3072 + j] + bih[3072 + j] + bhh[3072 + j];
  const float c2 = sigm(pf) * dc_in[m * 1024 + j] + sigm(pi) * tanh_(pg);
  const float h2 = sigm(po) * tanh_(c2);
  dhac[m * 1280 + j] = f2bf_rne(h2);
}

// ---------------------------------------------------------------------------
// K5 GEMM: proj partial = dhac(bf16) @ Wp^T, grid (4 n-tiles, 20 chunks of 64k)
// ---------------------------------------------------------------------------
__global__ __launch_bounds__(256) void k5_gemm(
    const u16* __restrict__ dhac, const float* __restrict__ Wp,
    float* __restrict__ proj)
{
  const int tid = threadIdx.x;
  const int w = tid >> 6, lane = tid & 63, quad = lane >> 4, l16 = lane & 15;
  const int n = blockIdx.x * 64 + w * 16 + l16, ks = blockIdx.y;
  const int kb0 = ks * 64;
  f32x4 acc[4] = {{0,0,0,0},{0,0,0,0},{0,0,0,0},{0,0,0,0}};
#pragma unroll
  for (int kb = kb0; kb < kb0 + 64; kb += 32) {
    const int k = kb + quad * 8;
    bf16x8 b_h, b_l; split8t(Wp + n * 1280 + k, b_h, b_l);
#pragma unroll
    for (int mt = 0; mt < 4; ++mt) {
      bf16x8 af = ldb(dhac + (mt * 16 + l16) * 1280 + k);
      acc[mt] = mfma16(af, b_h, acc[mt]);
      acc[mt] = mfma16(af, b_l, acc[mt]);
    }
  }
#pragma unroll
  for (int mt = 0; mt < 4; ++mt)
#pragma unroll
    for (int r = 0; r < 4; ++r)
      atomicAdd(&proj[(mt * 16 + quad * 4 + r) * 256 + n], acc[mt][r]);
}

// ---------------------------------------------------------------------------
// K5 epilogue: blocks 0..63 add bias -> out; blocks 64..79: stop gate dots.
// ---------------------------------------------------------------------------
__global__ __launch_bounds__(256) void k5_epi(
    const float* __restrict__ proj, const float* __restrict__ bp,
    const u16* __restrict__ dhac, const float* __restrict__ Wg,
    const float* __restrict__ bg, float* __restrict__ out)
{
  const int tid = threadIdx.x;
  if (blockIdx.x < 64) {
    const int m = blockIdx.x;
    out[m * 256 + tid] = proj[m * 256 + tid] + bp[tid];
  } else {
    const int w = tid >> 6, lane = tid & 63;
    const int bb = (blockIdx.x - 64) * 4 + w;
    float s = 0.0f;
    for (int k = lane; k < 1280; k += 64) s += bf2f(dhac[bb * 1280 + k]) * Wg[k];
    for (int off = 1; off < 64; off <<= 1) s += __shfl_xor(s, off, 64);
    if (lane == 0) out[16384 + bb] = s + bg[0];
  }
}

extern "C" void kernel_launch(void* const* d_in, const int* in_sizes, int n_in,
                              void* d_out, int out_size, void* d_ws, size_t ws_size,
                              hipStream_t stream)
{
  const float* lf    = (const float*)d_in[0];
  const float* ah0   = (const float*)d_in[1];
  const float* ac0   = (const float*)d_in[2];
  const float* aw    = (const float*)d_in[3];
  const float* awc   = (const float*)d_in[4];
  const float* actx  = (const float*)d_in[5];
  const float* dh0   = (const float*)d_in[6];
  const float* dc0   = (const float*)d_in[7];
  const float* mem   = (const float*)d_in[8];
  const float* pm    = (const float*)d_in[9];
  const float* Wih_a = (const float*)d_in[10];
  const float* Whh_a = (const float*)d_in[11];
  const float* bih_a = (const float*)d_in[12];
  const float* bhh_a = (const float*)d_in[13];
  const float* Wq    = (const float*)d_in[14];
  const float* Wv    = (const float*)d_in[15];
  const float* Wloc  = (const float*)d_in[16];
  const float* Wlfc  = (const float*)d_in[17];
  const float* Wih_d = (const float*)d_in[18];
  const float* Whh_d = (const float*)d_in[19];
  const float* bih_d = (const float*)d_in[20];
  const float* bhh_d = (const float*)d_in[21];
  const float* Wp    = (const float*)d_in[22];
  const float* bp    = (const float*)d_in[23];
  const float* Wg    = (const float*)d_in[24];
  const float* bg    = (const float*)d_in[25];
  const int* msk     = (const int*)d_in[26];

  // ---- workspace layout (fp32 offsets) ----
  float* wsf     = (float*)d_ws;
  float* gates_a = wsf;            // 262144  (zeroed)
  float* gates_d = wsf + 262144;   // 262144  (zeroed)
  float* proj    = wsf + 524288;   // 16384   (zeroed)
  float* ctx     = wsf + 540672;   // 16384   (zeroed)
  float* ah_f    = wsf + 557056;   // 65536
  float* pq      = wsf + 622592;   // 8192
  float* e_g     = wsf + 630784;   // 131072
  float* w_f     = wsf + 761856;   // 131072
  u16*  xd       = (u16*)(wsf + 892928);  // 64*1280 bf16
  u16*  dhac     = xd + 81920;            // 64*1280 bf16
  u16*  w2b      = dhac + 81920;          // 128*64 bf16

  float* out   = (float*)d_out;
  float* out_w = out + 16448;      // after proj(16384) + stop(64)

  hipMemsetAsync(d_ws, 0, 557056 * sizeof(float), stream);  // gates_a|gates_d|proj|ctx

  k0_prep    <<<64, 128, 0, stream>>>(Wloc, Wlfc, w2b);
  k1_gemm    <<<dim3(64, KSA), 256, 0, stream>>>(lf, actx, ah0, Wih_a, Whh_a, gates_a);
  k1_epi     <<<256, 256, 0, stream>>>(gates_a, ac0, bih_a, bhh_a, ah_f, xd);
  k2a_pq     <<<512, 256, 0, stream>>>(ah_f, Wq, pq);
  k2_energy  <<<dim3(64, 64), 256, 0, stream>>>(aw, awc, pm, Wv, pq, w2b, msk, e_g);
  k3a_softmax<<<64, 256, 0, stream>>>(e_g, w_f, out_w);
  k3b_ctx    <<<dim3(8, 64), 256, 0, stream>>>(w_f, mem, ctx);
  k3c_cvt    <<<64, 256, 0, stream>>>(ctx, xd, dhac);
  k4_gemm    <<<dim3(64, 9), 256, 0, stream>>>(xd, dh0, Wih_d, Whh_d, gates_d);
  k4_epi     <<<256, 256, 0, stream>>>(gates_d, dc0, bih_d, bhh_d, dhac);
  k5_gemm    <<<dim3(4, 20), 256, 0, stream>>>(dhac, Wp, proj);
  k5_epi     <<<80, 256, 0, stream>>>(proj, bp, dhac, Wg, bg, out);
}